// Round 5
// baseline (703.636 us; speedup 1.0000x reference)
//
#include <hip/hip_runtime.h>

// Correlation layer: out[b, dy*9+dx, y, x] =
//   (1/256) * sum_c frn[b,c,y,x] * fqn_pad[b,c,y+dy,x+dx]   (pad r=4)
// Identity: dot(frn,fqn) = dot(fr,fq) * invnorm(fr) * invnorm(fq).
//
// R5 = R3's pipelined structure + R4's register-cap fix.
// History: R3 (reg prefetch, (64,3) => 64-reg cap) spilled -> 897MB writes.
//          R4 (no prefetch, (64,2) => 128-reg cap) VGPR=52, no spill, but
//          chunk-serial: ~600cyc exposed latency per chunk, VALUBusy 23%.
// R5: fq halo prefetched 1 chunk ahead in v[5] (20 regs), fr rolled 1 chunk
// ahead in fra[4] (16 regs); est ~100 VGPR < 128 cap -> no spill, and chunk
// ch+1's global loads are in flight across chunk ch's ~480cyc FMA block.
// 1-wave blocks, wave-private LDS, zero __syncthreads (same-wave DS order).

#define BB 8
#define CC 256
#define HH 96
#define WW 128
#define HW (HH*WW)
#define CHW (CC*HW)
#define NDISP 81
#define TXS 64          // tile width: 16 tx * 4 px
#define TYS 4           // tile rows
#define HX4 18          // halo row width in float4 (72 floats = 64 + 8)
#define NSLOT (TYS*HX4) // 72 float4 slots per channel
#define CK 4            // channels per chunk
#define NCHK (CC/CK)    // 64 chunks
#define NST (NSLOT*CK)  // 288 float4 slots per chunk
#define NJ 5            // ceil(288/64) staging rounds
#define YT (HH/TYS)     // 24
#define XT 2
#define NTILES (BB*YT*XT) // 384
#define NGRP 9
#define EPSN 1e-12f

__global__ __launch_bounds__(64, 2) void corr_kernel(
    const float* __restrict__ fr, const float* __restrict__ fq,
    float* __restrict__ out)
{
    __shared__ float4 s_fq[NST];   // 4608 B, wave-private (1 wave/block)

    const int lane = threadIdx.x;
    const int tx   = lane & 15;    // 0..15, 4 px each
    const int ty   = lane >> 4;    // 0..3

    const int tile = blockIdx.x % NTILES;  // dy-copies at stride 384 ≡ 0 mod 8 → same XCD
    const int dy   = blockIdx.x / NTILES;  // 0..8
    const int b    = tile / (YT * XT);
    const int rem  = tile % (YT * XT);
    const int y0   = (rem >> 1) * TYS;
    const int x0   = (rem & 1) * TXS;

    // ---- staging slot ownership: slot i = c*72 + row*18 + col4, i = 64j+lane ----
    int soff[NJ]; bool sval[NJ];
#pragma unroll
    for (int j = 0; j < NJ; ++j) {
        int i = 64 * j + lane;
        bool act = (i < NST);
        int c    = i / NSLOT;       // chunk-local channel 0..3
        int s    = i % NSLOT;
        int row  = s / HX4;         // halo row == output row offset
        int col4 = s % HX4;
        int gy = y0 + dy - 4 + row;
        int gx = x0 - 4 + col4 * 4;
        sval[j] = act && ((unsigned)gy < (unsigned)HH) && ((unsigned)gx < (unsigned)WW);
        soff[j] = b * CHW + c * HW + gy * WW + gx;
        // pre-zero OOB slots once; they are OOB for every chunk, never rewritten
        if (act && !sval[j]) s_fq[i] = make_float4(0.f, 0.f, 0.f, 0.f);
    }

    const int frbase = b * CHW + (y0 + ty) * WW + x0 + tx * 4;

    // ---- prefetch chunk 0: fq halo into v[], fr into fra[] ----
    float4 v[NJ];
#pragma unroll
    for (int j = 0; j < NJ; ++j)
        if (sval[j]) v[j] = *(const float4*)(fq + soff[j]);
    float4 fra[CK];
#pragma unroll
    for (int c = 0; c < CK; ++c)
        fra[c] = *(const float4*)(fr + frbase + c * HW);

    float4 acc[9];
#pragma unroll
    for (int d = 0; d < 9; ++d) acc[d] = make_float4(0.f, 0.f, 0.f, 0.f);
    float sqn[12];
#pragma unroll
    for (int i = 0; i < 12; ++i) sqn[i] = 0.f;
    float4 fr2 = make_float4(0.f, 0.f, 0.f, 0.f);

#pragma unroll 1
    for (int ch = 0; ch < NCHK; ++ch) {
        const int nch = (ch + 1 < NCHK) ? ch + 1 : ch;   // last iter: dead reload
        const int nco = nch * (CK * HW);

        // ---- commit current chunk to LDS; launch next chunk's fq loads ----
#pragma unroll
        for (int j = 0; j < NJ; ++j) {
            if (sval[j]) {
                s_fq[64 * j + lane] = v[j];
                v[j] = *(const float4*)(fq + soff[j] + nco);
            }
        }

        // ---- compute 4 channels; roll fr one chunk ahead ----
#pragma unroll
        for (int c = 0; c < CK; ++c) {
            float4 a = fra[c];
            fra[c] = *(const float4*)(fr + frbase + nco + c * HW);
            fr2.x += a.x * a.x; fr2.y += a.y * a.y;
            fr2.z += a.z * a.z; fr2.w += a.w * a.w;

            float rw[12];
#pragma unroll
            for (int s4 = 0; s4 < 3; ++s4) {
                float4 t = s_fq[c * NSLOT + ty * HX4 + tx + s4];
                rw[s4 * 4 + 0] = t.x;
                rw[s4 * 4 + 1] = t.y;
                rw[s4 * 4 + 2] = t.z;
                rw[s4 * 4 + 3] = t.w;
            }
#pragma unroll
            for (int i = 0; i < 12; ++i) sqn[i] += rw[i] * rw[i];
#pragma unroll
            for (int dx = 0; dx < 9; ++dx) {
                acc[dx].x += a.x * rw[dx + 0];
                acc[dx].y += a.y * rw[dx + 1];
                acc[dx].z += a.z * rw[dx + 2];
                acc[dx].w += a.w * rw[dx + 3];
            }
        }
    }

    // ---- epilogue: all norms in registers ----
    float inq[12];
#pragma unroll
    for (int i = 0; i < 12; ++i)
        inq[i] = 1.0f / fmaxf(sqrtf(sqn[i]), EPSN);

    float4 ir;
    ir.x = 1.0f / fmaxf(sqrtf(fr2.x), EPSN);
    ir.y = 1.0f / fmaxf(sqrtf(fr2.y), EPSN);
    ir.z = 1.0f / fmaxf(sqrtf(fr2.z), EPSN);
    ir.w = 1.0f / fmaxf(sqrtf(fr2.w), EPSN);

    const float inv256 = 1.0f / 256.0f;
    const int obase = (b * NDISP + dy * 9) * HW + (y0 + ty) * WW + x0 + tx * 4;
#pragma unroll
    for (int dx = 0; dx < 9; ++dx) {
        float4 a = acc[dx];
        float4 o;
        o.x = a.x * ir.x * inq[dx + 0] * inv256;
        o.y = a.y * ir.y * inq[dx + 1] * inv256;
        o.z = a.z * ir.z * inq[dx + 2] * inv256;
        o.w = a.w * ir.w * inq[dx + 3] * inv256;
        *(float4*)(out + obase + dx * HW) = o;
    }
}

extern "C" void kernel_launch(void* const* d_in, const int* in_sizes, int n_in,
                              void* d_out, int out_size, void* d_ws, size_t ws_size,
                              hipStream_t stream) {
    const float* fr = (const float*)d_in[0];
    const float* fq = (const float*)d_in[1];
    float* out = (float*)d_out;
    corr_kernel<<<dim3(NTILES * NGRP), dim3(64), 0, stream>>>(fr, fq, out);
}

// Round 6
// 490.498 us; speedup vs baseline: 1.4345x; 1.4345x over previous
//
#include <hip/hip_runtime.h>

// Correlation layer: out[b, dy*9+dx, y, x] =
//   (1/256) * sum_c frn[b,c,y,x] * fqn_pad[b,c,y+dy,x+dx]   (pad r=4)
// Identity: dot(frn,fqn) = dot(fr,fq) * invnorm(fr) * invnorm(fq).
//
// R6 = R5's pipelined structure + allocator pinned via amdgpu_waves_per_eu.
// History: R3/R5 (prefetch) spilled at VGPR=64 -> ~880MB scratch writes,
//   VALUBusy 9%: launch_bounds only sets min waves/EU; allocator still
//   targets 8 waves (64-reg budget) and its spill heuristic chose spilling
//   over dropping occupancy. R4 (no prefetch, 52 regs) ran clean at 237us
//   but chunk-serial latency-bound (VALUBusy 23%).
// R6: waves_per_eu(1,4) -> 128-reg compile budget (grid-limits us to ~3.4
//   waves/SIMD anyway); prefetch defs unconditional (clamped-safe offsets,
//   guarded LDS commit only) to keep live ranges cheap. ~113 reg demand.
// 1-wave blocks, wave-private LDS, zero __syncthreads (same-wave DS order).

#define BB 8
#define CC 256
#define HH 96
#define WW 128
#define HW (HH*WW)
#define CHW (CC*HW)
#define NDISP 81
#define TXS 64          // tile width: 16 tx * 4 px
#define TYS 4           // tile rows
#define HX4 18          // halo row width in float4 (72 floats = 64 + 8)
#define NSLOT (TYS*HX4) // 72 float4 slots per channel
#define CK 4            // channels per chunk
#define NCHK (CC/CK)    // 64 chunks
#define NST (NSLOT*CK)  // 288 float4 slots per chunk
#define NJ 5            // ceil(288/64) staging rounds
#define YT (HH/TYS)     // 24
#define XT 2
#define NTILES (BB*YT*XT) // 384
#define NGRP 9
#define EPSN 1e-12f

__global__ __attribute__((amdgpu_waves_per_eu(1, 4))) __launch_bounds__(64)
void corr_kernel(
    const float* __restrict__ fr, const float* __restrict__ fq,
    float* __restrict__ out)
{
    __shared__ float4 s_fq[NST];   // 4608 B, wave-private (1 wave/block)

    const int lane = threadIdx.x;
    const int tx   = lane & 15;    // 0..15, 4 px each
    const int ty   = lane >> 4;    // 0..3

    const int tile = blockIdx.x % NTILES;  // dy-copies at stride 384 ≡ 0 mod 8 → same XCD
    const int dy   = blockIdx.x / NTILES;  // 0..8
    const int b    = tile / (YT * XT);
    const int rem  = tile % (YT * XT);
    const int y0   = (rem >> 1) * TYS;
    const int x0   = (rem & 1) * TXS;

    // ---- staging slot ownership: slot i = c*72 + row*18 + col4, i = 64j+lane ----
    // soff is clamped to a safe address for invalid lanes; loads are
    // unconditional (cheap liveness), only the LDS commit is guarded.
    int soff[NJ]; bool sval[NJ];
#pragma unroll
    for (int j = 0; j < NJ; ++j) {
        int i = 64 * j + lane;
        bool act = (i < NST);
        int c    = i / NSLOT;       // chunk-local channel 0..3
        int s    = i % NSLOT;
        int row  = s / HX4;         // halo row == output row offset
        int col4 = s % HX4;
        int gy = y0 + dy - 4 + row;
        int gx = x0 - 4 + col4 * 4;
        sval[j] = act && ((unsigned)gy < (unsigned)HH) && ((unsigned)gx < (unsigned)WW);
        soff[j] = sval[j] ? (b * CHW + c * HW + gy * WW + gx) : 0;
        // pre-zero OOB slots once; they are never rewritten
        if (act && !sval[j]) s_fq[i] = make_float4(0.f, 0.f, 0.f, 0.f);
    }

    const int frbase = b * CHW + (y0 + ty) * WW + x0 + tx * 4;

    // ---- prefetch chunk 0: fq halo into v[], fr into fra[] ----
    float4 v[NJ];
#pragma unroll
    for (int j = 0; j < NJ; ++j)
        v[j] = *(const float4*)(fq + soff[j]);
    float4 fra[CK];
#pragma unroll
    for (int c = 0; c < CK; ++c)
        fra[c] = *(const float4*)(fr + frbase + c * HW);

    float4 acc[9];
#pragma unroll
    for (int d = 0; d < 9; ++d) acc[d] = make_float4(0.f, 0.f, 0.f, 0.f);
    float sqn[12];
#pragma unroll
    for (int i = 0; i < 12; ++i) sqn[i] = 0.f;
    float4 fr2 = make_float4(0.f, 0.f, 0.f, 0.f);

#pragma unroll 1
    for (int ch = 0; ch < NCHK; ++ch) {
        const int nch = (ch + 1 < NCHK) ? ch + 1 : ch;   // last iter: dead reload
        const int nco = nch * (CK * HW);

        // ---- commit current chunk to LDS; launch next chunk's fq loads ----
#pragma unroll
        for (int j = 0; j < NJ; ++j) {
            if (sval[j]) s_fq[64 * j + lane] = v[j];
            v[j] = *(const float4*)(fq + soff[j] + nco);
        }

        // ---- compute 4 channels; roll fr one chunk ahead ----
#pragma unroll
        for (int c = 0; c < CK; ++c) {
            float4 a = fra[c];
            fra[c] = *(const float4*)(fr + frbase + nco + c * HW);
            fr2.x += a.x * a.x; fr2.y += a.y * a.y;
            fr2.z += a.z * a.z; fr2.w += a.w * a.w;

            float rw[12];
#pragma unroll
            for (int s4 = 0; s4 < 3; ++s4) {
                float4 t = s_fq[c * NSLOT + ty * HX4 + tx + s4];
                rw[s4 * 4 + 0] = t.x;
                rw[s4 * 4 + 1] = t.y;
                rw[s4 * 4 + 2] = t.z;
                rw[s4 * 4 + 3] = t.w;
            }
#pragma unroll
            for (int i = 0; i < 12; ++i) sqn[i] += rw[i] * rw[i];
#pragma unroll
            for (int dx = 0; dx < 9; ++dx) {
                acc[dx].x += a.x * rw[dx + 0];
                acc[dx].y += a.y * rw[dx + 1];
                acc[dx].z += a.z * rw[dx + 2];
                acc[dx].w += a.w * rw[dx + 3];
            }
        }
    }

    // ---- epilogue: all norms in registers ----
    float inq[12];
#pragma unroll
    for (int i = 0; i < 12; ++i)
        inq[i] = 1.0f / fmaxf(sqrtf(sqn[i]), EPSN);

    float4 ir;
    ir.x = 1.0f / fmaxf(sqrtf(fr2.x), EPSN);
    ir.y = 1.0f / fmaxf(sqrtf(fr2.y), EPSN);
    ir.z = 1.0f / fmaxf(sqrtf(fr2.z), EPSN);
    ir.w = 1.0f / fmaxf(sqrtf(fr2.w), EPSN);

    const float inv256 = 1.0f / 256.0f;
    const int obase = (b * NDISP + dy * 9) * HW + (y0 + ty) * WW + x0 + tx * 4;
#pragma unroll
    for (int dx = 0; dx < 9; ++dx) {
        float4 a = acc[dx];
        float4 o;
        o.x = a.x * ir.x * inq[dx + 0] * inv256;
        o.y = a.y * ir.y * inq[dx + 1] * inv256;
        o.z = a.z * ir.z * inq[dx + 2] * inv256;
        o.w = a.w * ir.w * inq[dx + 3] * inv256;
        *(float4*)(out + obase + dx * HW) = o;
    }
}

extern "C" void kernel_launch(void* const* d_in, const int* in_sizes, int n_in,
                              void* d_out, int out_size, void* d_ws, size_t ws_size,
                              hipStream_t stream) {
    const float* fr = (const float*)d_in[0];
    const float* fq = (const float*)d_in[1];
    float* out = (float*)d_out;
    corr_kernel<<<dim3(NTILES * NGRP), dim3(64), 0, stream>>>(fr, fq, out);
}

// Round 7
// 322.246 us; speedup vs baseline: 2.1835x; 1.5221x over previous
//
#include <hip/hip_runtime.h>

// Correlation layer: out[b, dy*9+dx, y, x] =
//   (1/256) * sum_c frn[b,c,y,x] * fqn_pad[b,c,y+dy,x+dx]   (pad r=4)
// Identity: dot(frn,fqn) = dot(fr,fq) * invnorm(fr) * invnorm(fq).
//
// R7: async-DMA pipeline. History: R3/R5 spilled fq prefetch to scratch
// (880MB writes), R6 spilled it to LDS (LDS 4608->9728) — allocator refuses
// a register-resident fq prefetch. Fix: fq never touches VGPRs —
// global_load_lds DMA into double-buffered LDS, explicit s_waitcnt vmcnt(9)
// (never 0) keeps next chunk's 5 DMA + 4 fr loads in flight across the
// current chunk's FMA block. 1 wave/block => zero barriers.
// DMA count must be runtime-uniform (5/iter) for the vmcnt math: OOB halo
// lanes are CLAMP-addressed (not masked); zero-pad semantics enforced by
// an epilogue mask (out=0 where the fq pixel is OOB == reference zero-pad).

#define BB 8
#define CC 256
#define HH 96
#define WW 128
#define HW (HH*WW)
#define CHW (CC*HW)
#define NDISP 81
#define TYS 4          // rows per wave-tile
#define HX4 18         // halo row width in float4 (72 floats = 64 + 8)
#define NSLOT (TYS*HX4) // 72 float4 slots per channel
#define CK 4           // channels per chunk
#define NCHK (CC/CK)   // 64 chunks
#define NST (NSLOT*CK) // 288 float4 slots per chunk
#define YT (HH/TYS)    // 24
#define XT 2
#define NTILES (BB*YT*XT) // 384
#define NGRP 9
#define EPSN 1e-12f

__device__ __forceinline__ void dma16(const void* g, void* l) {
    __builtin_amdgcn_global_load_lds(
        (const __attribute__((address_space(1))) void*)g,
        (__attribute__((address_space(3))) void*)l,
        16, 0, 0);
}

__global__ __launch_bounds__(64) __attribute__((amdgpu_waves_per_eu(4, 4)))
void corr_kernel(
    const float* __restrict__ fr, const float* __restrict__ fq,
    float* __restrict__ out)
{
    __shared__ float4 s_fq[2][NST];   // 9216 B, double-buffered fq halo chunk

    const int lane = threadIdx.x;
    const int tx   = lane & 15;    // 0..15, 4 px each
    const int ty   = lane >> 4;    // 0..3

    const int tile = blockIdx.x % NTILES;  // dy-copies at stride 384 ≡ 0 mod 8 → same XCD
    const int dy   = blockIdx.x / NTILES;  // 0..8
    const int b    = tile / (YT * XT);
    const int rem  = tile % (YT * XT);
    const int y0   = (rem >> 1) * TYS;
    const int x0   = (rem & 1) * 64;

    // ---- staging addresses: slot i = 64j+lane -> (c=i/72, row=(i%72)/18, col4=i%18)
    // OOB rows/cols clamped to valid addresses (garbage data; masked at epilogue).
    int soff[5];
#pragma unroll
    for (int j = 0; j < 5; ++j) {
        int i = 64 * j + lane;
        int c    = (i / NSLOT) & 3;   // &3: j=4 upper lanes never DMA'd, keep addr safe
        int s    = i % NSLOT;
        int row  = s / HX4;
        int col4 = s % HX4;
        int gy = y0 + dy - 4 + row;
        int gx = x0 - 4 + col4 * 4;
        gy = min(max(gy, 0), HH - 1);
        gx = min(max(gx, 0), WW - 4);   // stays 16B-aligned
        soff[j] = b * CHW + c * HW + gy * WW + gx;
    }

    const int frbase = b * CHW + (y0 + ty) * WW + x0 + tx * 4;

    // ---- preamble: DMA chunk 0 -> buf0 (5 events), fr chunk 0 -> regs (4 events)
#pragma unroll
    for (int j = 0; j < 4; ++j)
        dma16(fq + soff[j], &s_fq[0][64 * j]);
    if (lane < 32)                       // 32 tail slots; exec never empty
        dma16(fq + soff[4], &s_fq[0][256]);

    float4 fra[CK];
#pragma unroll
    for (int c = 0; c < CK; ++c)
        fra[c] = *(const float4*)(fr + frbase + c * HW);

    float4 acc[9];
#pragma unroll
    for (int d = 0; d < 9; ++d) acc[d] = make_float4(0.f, 0.f, 0.f, 0.f);
    float sqn[12];
#pragma unroll
    for (int i = 0; i < 12; ++i) sqn[i] = 0.f;
    float4 fr2 = make_float4(0.f, 0.f, 0.f, 0.f);

#pragma unroll 1
    for (int ch = 0; ch < NCHK; ++ch) {
        const int p   = ch & 1;
        const int nch = (ch + 1 < NCHK) ? ch + 1 : ch;   // last iter: dead re-issue
        const int nco = nch * (CK * HW);                 // keeps vmcnt count uniform

        // ---- issue next chunk's 5 DMAs into the other buffer ----
#pragma unroll
        for (int j = 0; j < 4; ++j)
            dma16(fq + soff[j] + nco, &s_fq[1 - p][64 * j]);
        if (lane < 32)
            dma16(fq + soff[4] + nco, &s_fq[1 - p][256]);

        // Drain everything older than the 9 just/soon-issued next-chunk ops:
        // prev 5 DMA (this chunk's fq) done; prev 4 fr covered by reg deps.
        __builtin_amdgcn_s_waitcnt(0x0F79);   // vmcnt(9), no lgkm/exp wait
        __builtin_amdgcn_sched_barrier(0);    // nothing hoists above the wait

        // ---- compute 4 channels from buf p; roll fr one chunk ahead ----
#pragma unroll
        for (int c = 0; c < CK; ++c) {
            float4 a = fra[c];
            fra[c] = *(const float4*)(fr + frbase + nco + c * HW);
            fr2.x += a.x * a.x; fr2.y += a.y * a.y;
            fr2.z += a.z * a.z; fr2.w += a.w * a.w;

            float rw[12];
#pragma unroll
            for (int s4 = 0; s4 < 3; ++s4) {
                float4 t = s_fq[p][c * NSLOT + ty * HX4 + tx + s4];
                rw[s4 * 4 + 0] = t.x;
                rw[s4 * 4 + 1] = t.y;
                rw[s4 * 4 + 2] = t.z;
                rw[s4 * 4 + 3] = t.w;
            }
#pragma unroll
            for (int i = 0; i < 12; ++i) sqn[i] += rw[i] * rw[i];
#pragma unroll
            for (int dx = 0; dx < 9; ++dx) {
                acc[dx].x += a.x * rw[dx + 0];
                acc[dx].y += a.y * rw[dx + 1];
                acc[dx].z += a.z * rw[dx + 2];
                acc[dx].w += a.w * rw[dx + 3];
            }
        }
    }

    // drain dead-issued DMAs before LDS is freed at endpgm
    __builtin_amdgcn_s_waitcnt(0x0F70);   // vmcnt(0)

    // ---- epilogue: norms in registers + OOB mask (== reference zero-pad) ----
    float inq[12];
#pragma unroll
    for (int i = 0; i < 12; ++i)
        inq[i] = 1.0f / fmaxf(sqrtf(sqn[i]), EPSN);

    float4 ir;
    ir.x = 1.0f / fmaxf(sqrtf(fr2.x), EPSN);
    ir.y = 1.0f / fmaxf(sqrtf(fr2.y), EPSN);
    ir.z = 1.0f / fmaxf(sqrtf(fr2.z), EPSN);
    ir.w = 1.0f / fmaxf(sqrtf(fr2.w), EPSN);

    const bool rowok = ((unsigned)(y0 + ty + dy - 4) < (unsigned)HH);
    const int  xe0   = x0 + tx * 4;
    const float inv256 = 1.0f / 256.0f;
    const int obase = (b * NDISP + dy * 9) * HW + (y0 + ty) * WW + xe0;
#pragma unroll
    for (int dx = 0; dx < 9; ++dx) {
        float4 a = acc[dx];
        float4 o;
        o.x = a.x * ir.x * inq[dx + 0] * inv256;
        o.y = a.y * ir.y * inq[dx + 1] * inv256;
        o.z = a.z * ir.z * inq[dx + 2] * inv256;
        o.w = a.w * ir.w * inq[dx + 3] * inv256;
        const int cb = xe0 + dx - 4;   // fq column for px .x at this dx
        o.x = (rowok && (unsigned)(cb    ) < (unsigned)WW) ? o.x : 0.f;
        o.y = (rowok && (unsigned)(cb + 1) < (unsigned)WW) ? o.y : 0.f;
        o.z = (rowok && (unsigned)(cb + 2) < (unsigned)WW) ? o.z : 0.f;
        o.w = (rowok && (unsigned)(cb + 3) < (unsigned)WW) ? o.w : 0.f;
        *(float4*)(out + obase + dx * HW) = o;
    }
}

extern "C" void kernel_launch(void* const* d_in, const int* in_sizes, int n_in,
                              void* d_out, int out_size, void* d_ws, size_t ws_size,
                              hipStream_t stream) {
    const float* fr = (const float*)d_in[0];
    const float* fq = (const float*)d_in[1];
    float* out = (float*)d_out;
    corr_kernel<<<dim3(NTILES * NGRP), dim3(64), 0, stream>>>(fr, fq, out);
}